// Round 9
// baseline (830.519 us; speedup 1.0000x reference)
//
#include <hip/hip_runtime.h>
#include <stdint.h>

#define NEGF  (-3.402823466e38f)
#define TOPK  64

typedef __attribute__((ext_vector_type(8))) short bfrag8;
typedef __attribute__((ext_vector_type(4))) float f32x4;
typedef __attribute__((ext_vector_type(16))) float f32x16;

static __device__ __forceinline__ unsigned short f2bf(float f) {
  union { float f; unsigned u; } c; c.f = f;
  unsigned u = c.u;
  return (unsigned short)((u + 0x7fffu + ((u >> 16) & 1u)) >> 16);
}
static __device__ __forceinline__ unsigned cvtpk_bf16(float lo, float hi) {
  unsigned r;
  asm("v_cvt_pk_bf16_f32 %0, %1, %2" : "=v"(r) : "v"(lo), "v"(hi));
  return r;
}
static __device__ __forceinline__ unsigned mono(float x) {
  union { float f; unsigned u; } c; c.f = x;
  return (c.u & 0x80000000u) ? ~c.u : (c.u | 0x80000000u);
}
static __device__ __forceinline__ float invmono(unsigned k) {
  union { unsigned u; float f; } c;
  c.u = (k & 0x80000000u) ? (k ^ 0x80000000u) : ~k;
  return c.f;
}
static __device__ __forceinline__ float waveSumF(float v) {
  #pragma unroll
  for (int o = 1; o < 64; o <<= 1) v += __shfl_xor(v, o);
  return v;
}
static __device__ __forceinline__ unsigned waveMaxU(unsigned v) {
  #pragma unroll
  for (int o = 1; o < 64; o <<= 1) {
    unsigned t = (unsigned)__shfl_xor((int)v, o);
    v = v > t ? v : t;
  }
  return v;
}
static __device__ __forceinline__ void gll16(const float* g, float* l) {
  __builtin_amdgcn_global_load_lds(
      (const __attribute__((address_space(1))) void*)g,
      (__attribute__((address_space(3))) void*)l, 16, 0, 0);
}

// ---------------- transpose: in f32 [R][C] -> out (f32 or bf16) [C][R] ----------------
template<int OBF>
__global__ __launch_bounds__(256) void transpose_k(const float* __restrict__ in,
                                                   void* __restrict__ out, int R, int C) {
  __shared__ float t[32][33];
  int c0 = blockIdx.x * 32, r0 = blockIdx.y * 32;
  int tx = threadIdx.x & 31, ty = (threadIdx.x >> 5) * 4;
  #pragma unroll
  for (int i = 0; i < 4; i++)
    t[ty + i][tx] = in[(size_t)(r0 + ty + i) * C + c0 + tx];
  __syncthreads();
  #pragma unroll
  for (int i = 0; i < 4; i++) {
    float v = t[tx][ty + i];
    size_t idx = (size_t)(c0 + ty + i) * R + r0 + tx;
    if (OBF) ((unsigned short*)out)[idx] = f2bf(v);
    else     ((float*)out)[idx] = v;
  }
}

// ---------------- per-z transpose: kp[z][2048][64] -> kpT[z][64][2048] ----------------
__global__ __launch_bounds__(256) void transpose_kp_kernel(const float* __restrict__ kp,
    float* __restrict__ kpT) {
  __shared__ float t[32][33];
  int z = blockIdx.z;
  const float* in = kp + (size_t)z * 2048 * 64;
  float* out = kpT + (size_t)z * 64 * 2048;
  int c0 = blockIdx.x * 32, r0 = blockIdx.y * 32;
  int tx = threadIdx.x & 31, ty = (threadIdx.x >> 5) * 4;
  #pragma unroll
  for (int i = 0; i < 4; i++)
    t[ty + i][tx] = in[(size_t)(r0 + ty + i) * 64 + c0 + tx];
  __syncthreads();
  #pragma unroll
  for (int i = 0; i < 4; i++)
    out[(size_t)(c0 + ty + i) * 2048 + r0 + tx] = t[tx][ty + i];
}

// ---------------- mask -> bit-packed ----------------
__global__ __launch_bounds__(256) void mask_pack_kernel(const int* __restrict__ mask,
    unsigned* __restrict__ mpack) {
  size_t idx = (size_t)blockIdx.x * 256 + threadIdx.x;
  int lane = threadIdx.x & 63;
  unsigned long long bal = __ballot(mask[idx] != 0);
  if (lane == 0)       mpack[idx >> 5] = (unsigned)bal;
  else if (lane == 32) mpack[idx >> 5] = (unsigned)(bal >> 32);
}

// ---------------- fp32 projection GEMM (q & k merged), 128x128 tile, k-major LDS ----------------
__global__ __launch_bounds__(256) void proj_f32_kernel(
    const float* __restrict__ q, const float* __restrict__ k,
    const float* __restrict__ WqT, const float* __restrict__ WkT,
    float* __restrict__ qp, float* __restrict__ kp) {
  __shared__ float AsT[64][132];
  __shared__ float BsT[64][132];
  int tid = threadIdx.x;
  int z = blockIdx.z;
  const float* A  = z ? k : q;
  const float* Bt = z ? WkT : WqT;
  float* out      = z ? kp : qp;
  float scale     = z ? 1.0f : 0.125f;
  int m0 = blockIdx.y * 128, n0 = blockIdx.x * 128;
  int lane = tid & 63, w = tid >> 6;
  int lx = lane & 15, ly = lane >> 4;
  int ra = w * 32 + ly * 4;
  int ca = lx * 4;
  int rr = tid >> 1;
  int kq0 = (tid & 1) << 5;
  float acc[8][8] = {};
  for (int k0 = 0; k0 < 512; k0 += 64) {
    const float* ar = A  + (size_t)(m0 + rr) * 512 + k0 + kq0;
    const float* br = Bt + (size_t)(n0 + rr) * 512 + k0 + kq0;
    #pragma unroll
    for (int s = 0; s < 8; s++) {
      float4 av = *(const float4*)(ar + (s << 2));
      float4 bv = *(const float4*)(br + (s << 2));
      int kk = kq0 + (s << 2);
      AsT[kk+0][rr] = av.x; AsT[kk+1][rr] = av.y; AsT[kk+2][rr] = av.z; AsT[kk+3][rr] = av.w;
      BsT[kk+0][rr] = bv.x; BsT[kk+1][rr] = bv.y; BsT[kk+2][rr] = bv.z; BsT[kk+3][rr] = bv.w;
    }
    __syncthreads();
    #pragma unroll 4
    for (int d = 0; d < 64; d++) {
      f32x4 a0 = *(const f32x4*)&AsT[d][ra];
      f32x4 a1 = *(const f32x4*)&AsT[d][ra + 16];
      f32x4 b0 = *(const f32x4*)&BsT[d][ca];
      f32x4 b1 = *(const f32x4*)&BsT[d][ca + 64];
      #pragma unroll
      for (int i = 0; i < 4; i++) {
        #pragma unroll
        for (int j = 0; j < 4; j++) {
          acc[i][j]     = fmaf(a0[i], b0[j], acc[i][j]);
          acc[i][j+4]   = fmaf(a0[i], b1[j], acc[i][j+4]);
          acc[i+4][j]   = fmaf(a1[i], b0[j], acc[i+4][j]);
          acc[i+4][j+4] = fmaf(a1[i], b1[j], acc[i+4][j+4]);
        }
      }
    }
    __syncthreads();
  }
  #pragma unroll
  for (int i = 0; i < 8; i++) {
    int m = m0 + ra + (i & 3) + ((i >> 2) << 4);
    int b = m >> 11, l = m & 2047;
    #pragma unroll
    for (int half = 0; half < 2; half++) {
      int n = n0 + ca + half * 64;
      int h = n >> 6, dd = n & 63;
      float4 v4;
      v4.x = acc[i][half*4+0]*scale; v4.y = acc[i][half*4+1]*scale;
      v4.z = acc[i][half*4+2]*scale; v4.w = acc[i][half*4+3]*scale;
      *(float4*)(out + ((((size_t)b*8 + h)*2048 + l)*64 + dd)) = v4;
    }
  }
}

// ---------------- FUSED logits + mask + exact top-64 + softmax (v5) ----------------
// grid (64 mb, 16 z), 512 thr (8 waves). Block: 32 rows; wave: 4 rows.
// B slab (4 d-rows x 2048 f32) double-buffered via async global_load_lds (no reg
// round-trip, no ds_writes); one barrier per iter. launch_bounds(512,1): let the
// allocator use real VGPRs (no 128-cap AGPR shuffling).
__global__ __launch_bounds__(512, 1) void ltk_kernel(
    const float* __restrict__ qp, const float* __restrict__ kpT,
    const unsigned* __restrict__ mpack, const float* __restrict__ qmaskf,
    float* __restrict__ probs) {
  __shared__ float As[32][68];
  __shared__ float Bs[2][4 * 2048];
  int tid = threadIdx.x;
  int lane = tid & 63, w = tid >> 6;
  int z = blockIdx.y, b = z >> 3;
  int m0 = blockIdx.x * 32;
  { // stage A (32x64 f32): 1 f32x4 per thread
    int r = tid >> 4, c4 = (tid & 15) << 2;
    *(f32x4*)&As[r][c4] = *(const f32x4*)(qp + (size_t)z * (2048*64) + (size_t)(m0 + r) * 64 + c4);
  }
  int sdd = tid >> 7, sc = (tid & 127) << 2;
  const float* Bp = kpT + (size_t)z * (64*2048);
  // async-stage slab 'slab' into Bs[bufi]: per-thread 4x global_load_lds(16B)
  #define STAGE_B(bufi, slab) do { \
    const float* s_ = Bp + (size_t)((slab) * 4 + sdd) * 2048 + sc; \
    float* d_ = &Bs[bufi][sdd * 2048 + sc]; \
    gll16(s_,        d_); \
    gll16(s_ + 512,  d_ + 512); \
    gll16(s_ + 1024, d_ + 1024); \
    gll16(s_ + 1536, d_ + 1536); \
  } while (0)
  STAGE_B(0, 0);
  float lg[4][8][4];
  #pragma unroll
  for (int r = 0; r < 4; r++)
    #pragma unroll
    for (int g = 0; g < 8; g++)
      #pragma unroll
      for (int i = 0; i < 4; i++) lg[r][g][i] = 0.f;
  int buf = 0;
  #pragma unroll 1
  for (int it = 0; it < 16; ++it) {
    __syncthreads();   // drains slab-it loads into Bs[buf]; frees Bs[buf^1] for reuse
    if (it < 15) STAGE_B(buf ^ 1, it + 1);   // latency hidden under this iter's FMAs
    f32x4 a0 = *(const f32x4*)&As[4*w+0][it*4];
    f32x4 a1 = *(const f32x4*)&As[4*w+1][it*4];
    f32x4 a2 = *(const f32x4*)&As[4*w+2][it*4];
    f32x4 a3 = *(const f32x4*)&As[4*w+3][it*4];
    const float* Bb = &Bs[buf][4*lane];
    #pragma unroll
    for (int g = 0; g < 8; ++g) {
      const float* bp = Bb + 256*g;
      f32x4 b0 = *(const f32x4*)(bp);
      f32x4 b1 = *(const f32x4*)(bp + 2048);
      f32x4 b2 = *(const f32x4*)(bp + 4096);
      f32x4 b3 = *(const f32x4*)(bp + 6144);
      #pragma unroll
      for (int i = 0; i < 4; ++i) {
        lg[0][g][i] = fmaf(a0[3], b3[i], fmaf(a0[2], b2[i], fmaf(a0[1], b1[i], fmaf(a0[0], b0[i], lg[0][g][i]))));
        lg[1][g][i] = fmaf(a1[3], b3[i], fmaf(a1[2], b2[i], fmaf(a1[1], b1[i], fmaf(a1[0], b0[i], lg[1][g][i]))));
        lg[2][g][i] = fmaf(a2[3], b3[i], fmaf(a2[2], b2[i], fmaf(a2[1], b1[i], fmaf(a2[0], b0[i], lg[2][g][i]))));
        lg[3][g][i] = fmaf(a3[3], b3[i], fmaf(a3[2], b2[i], fmaf(a3[1], b1[i], fmaf(a3[0], b0[i], lg[3][g][i]))));
      }
    }
    buf ^= 1;
  }
  #undef STAGE_B
  // ---- per-row exact top-64 + softmax; fully unrolled (compile-time lg/key indexing) ----
  int widx = lane >> 3, sh = (lane & 7) << 2;
  #pragma unroll
  for (int r = 0; r < 4; ++r) {
    int row = m0 + 4*w + r;
    const unsigned* mpr = mpack + ((size_t)b * 2048 + row) * 64;
    unsigned key[32];
    #pragma unroll
    for (int g = 0; g < 8; ++g) {
      unsigned nib = (mpr[8*g + widx] >> sh) & 0xFu;
      #pragma unroll
      for (int i = 0; i < 4; ++i)
        key[4*g+i] = mono(((nib >> i) & 1u) ? lg[r][g][i] : NEGF);
    }
    bool qm = qmaskf[b * 2048 + row] > 0.5f;
    unsigned drop = 0;
    if (qm) {
      // 1) binary search on hi16 (ballot/popcount)
      unsigned lo = 0u, hi = 0xFFFFu;
      while (lo < hi) {
        unsigned mid = lo + ((hi - lo + 1u) >> 1);
        unsigned t = mid << 16;
        int c = 0;
        #pragma unroll
        for (int e = 0; e < 32; e++) c += __popcll(__ballot(key[e] >= t));
        if (c >= TOPK) lo = mid; else hi = mid - 1u;
      }
      unsigned P = lo;
      unsigned hiMax = (P << 16) | 0xFFFFu;
      // 2) exact K64 among candidates with hi16==P
      int cgt_hi = 0;
      #pragma unroll
      for (int e = 0; e < 32; e++) cgt_hi += __popcll(__ballot(key[e] > hiMax));
      int remaining = TOPK - cgt_hi;
      unsigned cur = 0xFFFFFFFFu;
      unsigned K64 = P << 16;
      for (;;) {
        unsigned mx = 0;
        #pragma unroll
        for (int e = 0; e < 32; e++) {
          unsigned kk = key[e];
          if ((kk >> 16) == P && kk < cur) mx = mx > kk ? mx : kk;
        }
        mx = waveMaxU(mx);
        int ce = 0;
        #pragma unroll
        for (int e = 0; e < 32; e++) ce += __popcll(__ballot(key[e] == mx));
        if (remaining <= ce) { K64 = mx; break; }
        remaining -= ce;
        cur = mx;
      }
      // 3) drop mask
      int cgt = 0, ceqT = 0;
      #pragma unroll
      for (int e = 0; e < 32; e++) {
        cgt  += __popcll(__ballot(key[e] > K64));
        ceqT += __popcll(__ballot(key[e] == K64));
      }
      int rneed = TOPK - cgt;
      #pragma unroll
      for (int e = 0; e < 32; e++) if (key[e] < K64) drop |= (1u << e);
      if (ceqT > rneed) {
        // tie at boundary: keep lowest column indices; col = 256g + 4*lane + i
        int taken = 0;
        unsigned long long ltm = (1ull << lane) - 1ull;
        #pragma unroll
        for (int g = 0; g < 8; ++g) {
          bool e0 = key[4*g+0] == K64, e1 = key[4*g+1] == K64;
          bool e2 = key[4*g+2] == K64, e3 = key[4*g+3] == K64;
          unsigned long long bb0 = __ballot(e0), bb1 = __ballot(e1);
          unsigned long long bb2 = __ballot(e2), bb3 = __ballot(e3);
          int below = __popcll(bb0 & ltm) + __popcll(bb1 & ltm)
                    + __popcll(bb2 & ltm) + __popcll(bb3 & ltm);
          int base = taken + below, o = 0;
          if (e0) { if (base + o >= rneed) drop |= (1u << (4*g+0)); o++; }
          if (e1) { if (base + o >= rneed) drop |= (1u << (4*g+1)); o++; }
          if (e2) { if (base + o >= rneed) drop |= (1u << (4*g+2)); o++; }
          if (e3) { if (base + o >= rneed) drop |= (1u << (4*g+3)); o++; }
          taken += __popcll(bb0) + __popcll(bb1) + __popcll(bb2) + __popcll(bb3);
        }
      }
    }
    // softmax over kept
    unsigned kmax = 0;
    #pragma unroll
    for (int e = 0; e < 32; e++)
      if (!((drop >> e) & 1u)) kmax = kmax > key[e] ? kmax : key[e];
    kmax = waveMaxU(kmax);
    float mx = invmono(kmax);
    float ssum = 0.f;
    #pragma unroll
    for (int e = 0; e < 32; e++)
      if (!((drop >> e) & 1u)) ssum += __expf(invmono(key[e]) - mx);
    ssum = waveSumF(ssum);
    float inv = 1.0f / ssum;
    float* op = probs + ((size_t)z * 2048 + row) * 2048 + 4*lane;
    #pragma unroll
    for (int g = 0; g < 8; ++g) {
      float4 o;
      o.x = ((drop >> (4*g+0)) & 1u) ? 0.f : __expf(invmono(key[4*g+0]) - mx) * inv;
      o.y = ((drop >> (4*g+1)) & 1u) ? 0.f : __expf(invmono(key[4*g+1]) - mx) * inv;
      o.z = ((drop >> (4*g+2)) & 1u) ? 0.f : __expf(invmono(key[4*g+2]) - mx) * inv;
      o.w = ((drop >> (4*g+3)) & 1u) ? 0.f : __expf(invmono(key[4*g+3]) - mx) * inv;
      *(float4*)(op + 256*g) = o;
    }
  }
}

// ---------------- v_proj per-z ----------------
__global__ __launch_bounds__(256) void vproj_kernel(const float* __restrict__ v,
    const unsigned short* __restrict__ WvT, unsigned short* __restrict__ vpT) {
  __shared__ unsigned short As[128][64];
  __shared__ unsigned short Bs[128][64];
  int tid = threadIdx.x;
  int lane = tid & 63, wv = tid >> 6;
  int l31 = lane & 31, lh = lane >> 5;
  int wr = wv >> 1, wc = wv & 1;
  int z = blockIdx.z, b = z >> 3, h = z & 7;
  int m0 = blockIdx.y * 128, n0 = blockIdx.x * 128;
  const unsigned short* Ap = WvT + (size_t)(h * 512 + m0) * 512;
  const float* Bp = v + ((size_t)b * 2048 + n0) * 512;
  f32x16 acc[2][2];
  #pragma unroll
  for (int mf = 0; mf < 2; mf++)
    #pragma unroll
    for (int nf = 0; nf < 2; nf++)
      #pragma unroll
      for (int r = 0; r < 16; r++) acc[mf][nf][r] = 0.f;
  int srow = tid >> 1;
  int skc = (tid & 1) << 5;
  for (int k0 = 0; k0 < 512; k0 += 64) {
    {
      const bfrag8* s = (const bfrag8*)(Ap + (size_t)srow * 512 + k0 + skc);
      #pragma unroll
      for (int j = 0; j < 4; j++) {
        int c = (skc >> 3) + j;
        *(bfrag8*)&As[srow][((c + srow) & 7) * 8] = s[j];
      }
    }
    {
      const float* s = Bp + (size_t)srow * 512 + k0 + skc;
      #pragma unroll
      for (int j = 0; j < 4; j++) {
        float4 x0 = *(const float4*)(s + 8*j);
        float4 x1 = *(const float4*)(s + 8*j + 4);
        union { bfrag8 v; unsigned w[4]; } p;
        p.w[0] = cvtpk_bf16(x0.x, x0.y); p.w[1] = cvtpk_bf16(x0.z, x0.w);
        p.w[2] = cvtpk_bf16(x1.x, x1.y); p.w[3] = cvtpk_bf16(x1.z, x1.w);
        int c = (skc >> 3) + j;
        *(bfrag8*)&Bs[srow][((c + srow) & 7) * 8] = p.v;
      }
    }
    __syncthreads();
    #pragma unroll
    for (int ks = 0; ks < 4; ks++) {
      int qd = ks * 2 + lh;
      bfrag8 af[2], bfr[2];
      #pragma unroll
      for (int mf = 0; mf < 2; mf++) {
        int r = wr * 64 + mf * 32 + l31;
        af[mf] = *(const bfrag8*)&As[r][((qd + r) & 7) * 8];
      }
      #pragma unroll
      for (int nf = 0; nf < 2; nf++) {
        int n = wc * 64 + nf * 32 + l31;
        bfr[nf] = *(const bfrag8*)&Bs[n][((qd + n) & 7) * 8];
      }
      #pragma unroll
      for (int mf = 0; mf < 2; mf++)
        #pragma unroll
        for (int nf = 0; nf < 2; nf++)
          acc[mf][nf] = __builtin_amdgcn_mfma_f32_32x32x16_bf16(af[mf], bfr[nf], acc[mf][nf], 0, 0, 0);
    }
    __syncthreads();
  }
  #pragma unroll
  for (int mf = 0; mf < 2; mf++)
    #pragma unroll
    for (int nf = 0; nf < 2; nf++) {
      int l = n0 + wc * 64 + nf * 32 + l31;
      #pragma unroll
      for (int r = 0; r < 16; r++) {
        int d = m0 + wr * 64 + mf * 32 + (r & 3) + ((r >> 2) << 3) + (lh << 2);
        vpT[((size_t)z * 512 + d) * 2048 + l] = f2bf(acc[mf][nf][r]);
      }
    }
}

// ---------------- bf16 MFMA GEMM (fc only) ----------------
__global__ __launch_bounds__(256) void gemm_bf16_fc(const unsigned short* __restrict__ A,
    const unsigned short* __restrict__ Bt, float* __restrict__ Cout,
    int M, int N, int K) {
  __shared__ unsigned short As[64][72];
  __shared__ unsigned short Bs[128][72];
  int tid = threadIdx.x;
  int lane = tid & 63, wave = tid >> 6;
  int wr = wave >> 1, wc = wave & 1;
  int m0 = blockIdx.y * 64, n0 = blockIdx.x * 128;
  f32x4 acc[2][4];
  #pragma unroll
  for (int mi = 0; mi < 2; mi++)
    #pragma unroll
    for (int ni = 0; ni < 4; ni++) acc[mi][ni] = (f32x4){0.f, 0.f, 0.f, 0.f};
  int arow = tid >> 2, akc = (tid & 3) << 4;
  int brow = tid >> 1, bkc = (tid & 1) << 5;
  for (int k0 = 0; k0 < K; k0 += 64) {
    {
      const bfrag8* s = (const bfrag8*)(A + (size_t)(m0 + arow) * K + k0 + akc);
      *(bfrag8*)&As[arow][akc + 0] = s[0];
      *(bfrag8*)&As[arow][akc + 8] = s[1];
    }
    {
      const bfrag8* s = (const bfrag8*)(Bt + (size_t)(n0 + brow) * K + k0 + bkc);
      #pragma unroll
      for (int j = 0; j < 4; j++)
        *(bfrag8*)&Bs[brow][bkc + 8*j] = s[j];
    }
    __syncthreads();
    #pragma unroll
    for (int kh = 0; kh < 2; kh++) {
      int krd = (kh << 5) + ((lane >> 4) << 3);
      bfrag8 af[2], bfr[4];
      #pragma unroll
      for (int mi = 0; mi < 2; mi++)
        af[mi] = *(const bfrag8*)&As[wr*32 + mi*16 + (lane & 15)][krd];
      #pragma unroll
      for (int ni = 0; ni < 4; ni++)
        bfr[ni] = *(const bfrag8*)&Bs[wc*64 + ni*16 + (lane & 15)][krd];
      #pragma unroll
      for (int mi = 0; mi < 2; mi++)
        #pragma unroll
        for (int ni = 0; ni < 4; ni++)
          acc[mi][ni] = __builtin_amdgcn_mfma_f32_16x16x32_bf16(af[mi], bfr[ni], acc[mi][ni], 0, 0, 0);
    }
    __syncthreads();
  }
  #pragma unroll
  for (int mi = 0; mi < 2; mi++) {
    int rb = m0 + wr*32 + mi*16 + ((lane >> 4) << 2);
    #pragma unroll
    for (int ni = 0; ni < 4; ni++) {
      int col = n0 + wc*64 + ni*16 + (lane & 15);
      f32x4 v = acc[mi][ni];
      #pragma unroll
      for (int j = 0; j < 4; j++)
        Cout[(size_t)(rb + j)*512 + col] = v[j];
    }
  }
}

// ---------------- PV: probs[z] f32 x vpT[z] -> mixed bf16 ----------------
__global__ __launch_bounds__(512) void pv_kernel(const float* __restrict__ probs,
    const unsigned short* __restrict__ vpT, unsigned short* __restrict__ mixed) {
  __shared__ unsigned short As[64][64];
  __shared__ unsigned short Bs[512][64];
  int tid = threadIdx.x;
  int lane = tid & 63, wv = tid >> 6;
  int l31 = lane & 31, lh = lane >> 5;
  int bid = blockIdx.x;
  int xcd = bid & 7, idx = bid >> 3;
  int z = (xcd << 1) | (idx >> 5);
  int m0 = (idx & 31) << 6;
  const float* Ap = probs + (size_t)z * 2048 * 2048 + (size_t)m0 * 2048;
  const unsigned short* Bp = vpT + (size_t)z * 512 * 2048;
  f32x16 acc[2][2];
  #pragma unroll
  for (int mf = 0; mf < 2; mf++)
    #pragma unroll
    for (int nf = 0; nf < 2; nf++)
      #pragma unroll
      for (int r = 0; r < 16; r++) acc[mf][nf][r] = 0.f;
  int a_r = tid >> 3, a_c = tid & 7;
  for (int k0 = 0; k0 < 2048; k0 += 64) {
    {
      const float* s = Ap + (size_t)a_r * 2048 + k0 + a_c * 8;
      float4 x0 = *(const float4*)s;
      float4 x1 = *(const float4*)(s + 4);
      union { bfrag8 v; unsigned w[4]; } p;
      p.w[0] = cvtpk_bf16(x0.x, x0.y); p.w[1] = cvtpk_bf16(x0.z, x0.w);
      p.w[2] = cvtpk_bf16(x1.x, x1.y); p.w[3] = cvtpk_bf16(x1.z, x1.w);
      *(bfrag8*)&As[a_r][((a_c + a_r) & 7) * 8] = p.v;
    }
    #pragma unroll
    for (int s = 0; s < 8; s++) {
      int n = (tid >> 3) + (s << 6);
      bfrag8 vb = *(const bfrag8*)(Bp + (size_t)n * 2048 + k0 + a_c * 8);
      *(bfrag8*)&Bs[n][((a_c + n) & 7) * 8] = vb;
    }
    __syncthreads();
    #pragma unroll
    for (int ks = 0; ks < 4; ks++) {
      int qd = ks * 2 + lh;
      bfrag8 af[2], bfr[2];
      #pragma unroll
      for (int mf = 0; mf < 2; mf++) {
        int r = mf * 32 + l31;
        af[mf] = *(const bfrag8*)&As[r][((qd + r) & 7) * 8];
      }
      #pragma unroll
      for (int nf = 0; nf < 2; nf++) {
        int n = wv * 64 + nf * 32 + l31;
        bfr[nf] = *(const bfrag8*)&Bs[n][((qd + n) & 7) * 8];
      }
      #pragma unroll
      for (int mf = 0; mf < 2; mf++)
        #pragma unroll
        for (int nf = 0; nf < 2; nf++)
          acc[mf][nf] = __builtin_amdgcn_mfma_f32_32x32x16_bf16(af[mf], bfr[nf], acc[mf][nf], 0, 0, 0);
    }
    __syncthreads();
  }
  int bb = z >> 3, h = z & 7;
  #pragma unroll
  for (int mf = 0; mf < 2; mf++)
    #pragma unroll
    for (int nf = 0; nf < 2; nf++) {
      int n = wv * 64 + nf * 32 + l31;
      #pragma unroll
      for (int r = 0; r < 16; r++) {
        int row = m0 + mf * 32 + (r & 3) + ((r >> 2) << 3) + (lh << 2);
        mixed[((size_t)bb * 2048 + row) * 4096 + h * 512 + n] = f2bf(acc[mf][nf][r]);
      }
    }
}

extern "C" void kernel_launch(void* const* d_in, const int* in_sizes, int n_in,
                              void* d_out, int out_size, void* d_ws, size_t ws_size,
                              hipStream_t stream) {
  (void)in_sizes; (void)n_in; (void)out_size; (void)ws_size;
  const float* q     = (const float*)d_in[0];
  const float* k     = (const float*)d_in[1];
  const float* v     = (const float*)d_in[2];
  const int*   mask  = (const int*)d_in[3];
  const float* qmask = (const float*)d_in[4];
  const float* Wq    = (const float*)d_in[5];
  const float* Wk    = (const float*)d_in[6];
  const float* Wv    = (const float*)d_in[7];
  const float* Wfc   = (const float*)d_in[8];

  float* out   = (float*)d_out;                 // [2,2048,512]
  float* probs = out + 2097152;                 // [2,8,2048,2048]

  char* ws = (char*)d_ws;
  float*          qp    = (float*)(ws + 0);             // [16,2048,64] (q pre-scaled 1/8)
  float*          kp    = (float*)(ws + 8388608);       // [16,2048,64]
  unsigned short* vpT   = (unsigned short*)(ws + 16777216);  // [16,512,2048] bf16
  unsigned short* mixed = (unsigned short*)(ws + 50331648);  // [4096,4096] bf16
  float*          kpT   = (float*)(ws + 50331648);      // [16,64,2048] f32 (dead before pv writes mixed)
  unsigned*       mpack = (unsigned*)(ws + 58720256);   // [2,2048,64] u32 (inside mixed region)
  float*          WqT   = (float*)(ws + 83886080);      // [512,512]
  float*          WkT   = (float*)(ws + 84934656);      // [512,512]
  unsigned short* WvT   = (unsigned short*)(ws + 85983232);  // [4096,512] bf16
  unsigned short* WfcT  = (unsigned short*)(ws + 90177536);  // [512,4096] bf16

  transpose_k<0><<<dim3(16, 16),  256, 0, stream>>>(Wq,  WqT,  512, 512);
  transpose_k<0><<<dim3(16, 16),  256, 0, stream>>>(Wk,  WkT,  512, 512);
  transpose_k<1><<<dim3(128, 16), 256, 0, stream>>>(Wv,  WvT,  512, 4096);
  transpose_k<1><<<dim3(16, 128), 256, 0, stream>>>(Wfc, WfcT, 4096, 512);

  mask_pack_kernel<<<dim3(32768), 256, 0, stream>>>(mask, mpack);

  proj_f32_kernel<<<dim3(4, 32, 2), 256, 0, stream>>>(q, k, WqT, WkT, qp, kp);

  transpose_kp_kernel<<<dim3(2, 64, 16), 256, 0, stream>>>(kp, kpT);

  vproj_kernel<<<dim3(16, 4, 16), 256, 0, stream>>>(v, WvT, vpT);

  // FUSED: logits + mask + exact top-64 + softmax (async-LDS staged B, 32 rows/block)
  ltk_kernel<<<dim3(64, 16), 512, 0, stream>>>(qp, kpT, mpack, qmask, probs);

  pv_kernel<<<dim3(512), 512, 0, stream>>>(probs, vpT, mixed);

  gemm_bf16_fc<<<dim3(4, 64), 256, 0, stream>>>(mixed, WfcT, out, 4096, 512, 4096);
}

// Round 10
// 620.071 us; speedup vs baseline: 1.3394x; 1.3394x over previous
//
#include <hip/hip_runtime.h>
#include <stdint.h>

#define NEGF  (-3.402823466e38f)
#define TOPK  64

typedef __attribute__((ext_vector_type(8))) short bfrag8;
typedef __attribute__((ext_vector_type(4))) float f32x4;
typedef __attribute__((ext_vector_type(16))) float f32x16;

static __device__ __forceinline__ unsigned short f2bf(float f) {
  union { float f; unsigned u; } c; c.f = f;
  unsigned u = c.u;
  return (unsigned short)((u + 0x7fffu + ((u >> 16) & 1u)) >> 16);
}
static __device__ __forceinline__ unsigned cvtpk_bf16(float lo, float hi) {
  unsigned r;
  asm("v_cvt_pk_bf16_f32 %0, %1, %2" : "=v"(r) : "v"(lo), "v"(hi));
  return r;
}
static __device__ __forceinline__ unsigned mono(float x) {
  union { float f; unsigned u; } c; c.f = x;
  return (c.u & 0x80000000u) ? ~c.u : (c.u | 0x80000000u);
}
static __device__ __forceinline__ float invmono(unsigned k) {
  union { unsigned u; float f; } c;
  c.u = (k & 0x80000000u) ? (k ^ 0x80000000u) : ~k;
  return c.f;
}
static __device__ __forceinline__ float waveSumF(float v) {
  #pragma unroll
  for (int o = 1; o < 64; o <<= 1) v += __shfl_xor(v, o);
  return v;
}
static __device__ __forceinline__ unsigned waveMaxU(unsigned v) {
  #pragma unroll
  for (int o = 1; o < 64; o <<= 1) {
    unsigned t = (unsigned)__shfl_xor((int)v, o);
    v = v > t ? v : t;
  }
  return v;
}

// ---------------- transpose: in f32 [R][C] -> out (f32 or bf16) [C][R] ----------------
template<int OBF>
__global__ __launch_bounds__(256) void transpose_k(const float* __restrict__ in,
                                                   void* __restrict__ out, int R, int C) {
  __shared__ float t[32][33];
  int c0 = blockIdx.x * 32, r0 = blockIdx.y * 32;
  int tx = threadIdx.x & 31, ty = (threadIdx.x >> 5) * 4;
  #pragma unroll
  for (int i = 0; i < 4; i++)
    t[ty + i][tx] = in[(size_t)(r0 + ty + i) * C + c0 + tx];
  __syncthreads();
  #pragma unroll
  for (int i = 0; i < 4; i++) {
    float v = t[tx][ty + i];
    size_t idx = (size_t)(c0 + ty + i) * R + r0 + tx;
    if (OBF) ((unsigned short*)out)[idx] = f2bf(v);
    else     ((float*)out)[idx] = v;
  }
}

// ---------------- mask -> bit-packed ----------------
__global__ __launch_bounds__(256) void mask_pack_kernel(const int* __restrict__ mask,
    unsigned* __restrict__ mpack) {
  size_t idx = (size_t)blockIdx.x * 256 + threadIdx.x;
  int lane = threadIdx.x & 63;
  unsigned long long bal = __ballot(mask[idx] != 0);
  if (lane == 0)       mpack[idx >> 5] = (unsigned)bal;
  else if (lane == 32) mpack[idx >> 5] = (unsigned)(bal >> 32);
}

// ---------------- fp32 projection GEMM (q & k merged), 128x128 tile, k-major LDS ----------------
__global__ __launch_bounds__(256) void proj_f32_kernel(
    const float* __restrict__ q, const float* __restrict__ k,
    const float* __restrict__ WqT, const float* __restrict__ WkT,
    float* __restrict__ qp, float* __restrict__ kp) {
  __shared__ float AsT[64][132];
  __shared__ float BsT[64][132];
  int tid = threadIdx.x;
  int z = blockIdx.z;
  const float* A  = z ? k : q;
  const float* Bt = z ? WkT : WqT;
  float* out      = z ? kp : qp;
  float scale     = z ? 1.0f : 0.125f;
  int m0 = blockIdx.y * 128, n0 = blockIdx.x * 128;
  int lane = tid & 63, w = tid >> 6;
  int lx = lane & 15, ly = lane >> 4;
  int ra = w * 32 + ly * 4;
  int ca = lx * 4;
  int rr = tid >> 1;
  int kq0 = (tid & 1) << 5;
  float acc[8][8] = {};
  for (int k0 = 0; k0 < 512; k0 += 64) {
    const float* ar = A  + (size_t)(m0 + rr) * 512 + k0 + kq0;
    const float* br = Bt + (size_t)(n0 + rr) * 512 + k0 + kq0;
    #pragma unroll
    for (int s = 0; s < 8; s++) {
      float4 av = *(const float4*)(ar + (s << 2));
      float4 bv = *(const float4*)(br + (s << 2));
      int kk = kq0 + (s << 2);
      AsT[kk+0][rr] = av.x; AsT[kk+1][rr] = av.y; AsT[kk+2][rr] = av.z; AsT[kk+3][rr] = av.w;
      BsT[kk+0][rr] = bv.x; BsT[kk+1][rr] = bv.y; BsT[kk+2][rr] = bv.z; BsT[kk+3][rr] = bv.w;
    }
    __syncthreads();
    #pragma unroll 4
    for (int d = 0; d < 64; d++) {
      f32x4 a0 = *(const f32x4*)&AsT[d][ra];
      f32x4 a1 = *(const f32x4*)&AsT[d][ra + 16];
      f32x4 b0 = *(const f32x4*)&BsT[d][ca];
      f32x4 b1 = *(const f32x4*)&BsT[d][ca + 64];
      #pragma unroll
      for (int i = 0; i < 4; i++) {
        #pragma unroll
        for (int j = 0; j < 4; j++) {
          acc[i][j]     = fmaf(a0[i], b0[j], acc[i][j]);
          acc[i][j+4]   = fmaf(a0[i], b1[j], acc[i][j+4]);
          acc[i+4][j]   = fmaf(a1[i], b0[j], acc[i+4][j]);
          acc[i+4][j+4] = fmaf(a1[i], b1[j], acc[i+4][j+4]);
        }
      }
    }
    __syncthreads();
  }
  #pragma unroll
  for (int i = 0; i < 8; i++) {
    int m = m0 + ra + (i & 3) + ((i >> 2) << 4);
    int b = m >> 11, l = m & 2047;
    #pragma unroll
    for (int half = 0; half < 2; half++) {
      int n = n0 + ca + half * 64;
      int h = n >> 6, dd = n & 63;
      float4 v4;
      v4.x = acc[i][half*4+0]*scale; v4.y = acc[i][half*4+1]*scale;
      v4.z = acc[i][half*4+2]*scale; v4.w = acc[i][half*4+3]*scale;
      *(float4*)(out + ((((size_t)b*8 + h)*2048 + l)*64 + dd)) = v4;
    }
  }
}

// ---------------- fp32 logits GEMM, K=64 single-stage, fused bit-packed mask ----------------
// grid (16 nb, 16 mb, 16 z), 256 thr. Tile 128x128, per-thread 8x8.
__global__ __launch_bounds__(256) void logits_mask_kernel(
    const float* __restrict__ qp, const float* __restrict__ kp,
    const unsigned* __restrict__ mpack, float* __restrict__ out) {
  __shared__ float AsT[64][132];   // [k][m]
  __shared__ float BsT[64][132];   // [k][n]
  int tid = threadIdx.x;
  int z = blockIdx.z, b = z >> 3;
  int m0 = blockIdx.y * 128, n0 = blockIdx.x * 128;
  const float* Ap = qp + (size_t)z * (2048 * 64);
  const float* Bp = kp + (size_t)z * (2048 * 64);
  {
    int rr = tid >> 2;
    int kq = (tid & 3) << 2;
    #pragma unroll
    for (int pass = 0; pass < 2; pass++) {
      int r = rr + (pass << 6);
      const float* ar = Ap + (size_t)(m0 + r) * 64 + kq;
      const float* br = Bp + (size_t)(n0 + r) * 64 + kq;
      #pragma unroll
      for (int s = 0; s < 4; s++) {
        float4 av = *(const float4*)(ar + (s << 4));
        float4 bv = *(const float4*)(br + (s << 4));
        int k = kq + (s << 4);
        AsT[k+0][r] = av.x; AsT[k+1][r] = av.y; AsT[k+2][r] = av.z; AsT[k+3][r] = av.w;
        BsT[k+0][r] = bv.x; BsT[k+1][r] = bv.y; BsT[k+2][r] = bv.z; BsT[k+3][r] = bv.w;
      }
    }
  }
  __syncthreads();
  int lane = tid & 63, w = tid >> 6;
  int lx = lane & 15, ly = lane >> 4;
  int ra = w * 32 + ly * 4;
  int ca = lx * 4;
  float acc[8][8] = {};
  #pragma unroll 4
  for (int d = 0; d < 64; d++) {
    f32x4 a0 = *(const f32x4*)&AsT[d][ra];
    f32x4 a1 = *(const f32x4*)&AsT[d][ra + 16];
    f32x4 b0 = *(const f32x4*)&BsT[d][ca];
    f32x4 b1 = *(const f32x4*)&BsT[d][ca + 64];
    #pragma unroll
    for (int i = 0; i < 4; i++) {
      #pragma unroll
      for (int j = 0; j < 4; j++) {
        acc[i][j]     = fmaf(a0[i], b0[j], acc[i][j]);
        acc[i][j+4]   = fmaf(a0[i], b1[j], acc[i][j+4]);
        acc[i+4][j]   = fmaf(a1[i], b0[j], acc[i+4][j]);
        acc[i+4][j+4] = fmaf(a1[i], b1[j], acc[i+4][j+4]);
      }
    }
  }
  size_t outbase = (size_t)z * 2048 * 2048;
  const unsigned* mpb = mpack + (size_t)b * 2048 * 64;
  int w0i = (n0 + ca) >> 5, s0 = ca & 31;
  int w1i = (n0 + ca + 64) >> 5;
  #pragma unroll
  for (int i = 0; i < 8; i++) {
    int row = m0 + ra + (i & 3) + ((i >> 2) << 4);
    const unsigned* mpr = mpb + (size_t)row * 64;
    float* op = out + outbase + (size_t)row * 2048 + n0;
    unsigned nib0 = (mpr[w0i] >> s0) & 0xFu;
    unsigned nib1 = (mpr[w1i] >> s0) & 0xFu;
    float4 o0, o1;
    o0.x = (nib0 & 1u) ? acc[i][0] : NEGF;
    o0.y = (nib0 & 2u) ? acc[i][1] : NEGF;
    o0.z = (nib0 & 4u) ? acc[i][2] : NEGF;
    o0.w = (nib0 & 8u) ? acc[i][3] : NEGF;
    o1.x = (nib1 & 1u) ? acc[i][4] : NEGF;
    o1.y = (nib1 & 2u) ? acc[i][5] : NEGF;
    o1.z = (nib1 & 4u) ? acc[i][6] : NEGF;
    o1.w = (nib1 & 8u) ? acc[i][7] : NEGF;
    *(float4*)(op + ca) = o0;
    *(float4*)(op + ca + 64) = o1;
  }
}

// ---------------- per-row top-k + softmax (one wave per row, in-place) ----------------
// ballot/popcount counting; exp recomputed to keep VGPRs low.
__global__ __launch_bounds__(256) void topk_softmax_k(float* __restrict__ probs,
    const float* __restrict__ qmaskf) {
  int lane = threadIdx.x & 63;
  int row = blockIdx.x * 4 + (threadIdx.x >> 6);
  int b = row >> 14, q = row & 2047;
  float* rp = probs + (size_t)row * 2048;
  unsigned key[32];
  #pragma unroll
  for (int j = 0; j < 8; j++) {
    int base = (lane << 2) + (j << 8);
    float4 v = *(const float4*)(rp + base);
    key[4*j+0] = mono(v.x);
    key[4*j+1] = mono(v.y);
    key[4*j+2] = mono(v.z);
    key[4*j+3] = mono(v.w);
  }
  unsigned drop = 0;
  bool qm = qmaskf[b * 2048 + q] > 0.5f;
  if (qm) {
    unsigned lo = 0u, hi = 0xFFFFu;
    while (lo < hi) {
      unsigned mid = lo + ((hi - lo + 1u) >> 1);
      unsigned t = mid << 16;
      int c = 0;
      #pragma unroll
      for (int e = 0; e < 32; e++) c += __popcll(__ballot(key[e] >= t));
      if (c >= TOPK) lo = mid; else hi = mid - 1u;
    }
    unsigned P = lo;
    unsigned hiMax = (P << 16) | 0xFFFFu;
    int cgt_hi = 0;
    #pragma unroll
    for (int e = 0; e < 32; e++) cgt_hi += __popcll(__ballot(key[e] > hiMax));
    int remaining = TOPK - cgt_hi;
    unsigned cur = 0xFFFFFFFFu;
    unsigned K64 = P << 16;
    for (;;) {
      unsigned mx = 0;
      #pragma unroll
      for (int e = 0; e < 32; e++) {
        unsigned kk = key[e];
        if ((kk >> 16) == P && kk < cur) mx = mx > kk ? mx : kk;
      }
      mx = waveMaxU(mx);
      int ce = 0;
      #pragma unroll
      for (int e = 0; e < 32; e++) ce += __popcll(__ballot(key[e] == mx));
      if (remaining <= ce) { K64 = mx; break; }
      remaining -= ce;
      cur = mx;
    }
    int cgt = 0, ceqT = 0;
    #pragma unroll
    for (int e = 0; e < 32; e++) {
      cgt  += __popcll(__ballot(key[e] > K64));
      ceqT += __popcll(__ballot(key[e] == K64));
    }
    int r = TOPK - cgt;
    #pragma unroll
    for (int e = 0; e < 32; e++) if (key[e] < K64) drop |= (1u << e);
    if (ceqT > r) {
      // tie at boundary: keep lowest column indices; col = 4*lane... wait: col = lane*4+... no:
      // layout: key[4j+t] holds col = lane*4? NO — col = (lane<<2)+(j<<8) + t  -> order (j, lane, t)
      int taken = 0;
      unsigned long long ltm = (1ull << lane) - 1ull;
      for (int j = 0; j < 8; ++j) {
        bool e0 = key[4*j+0] == K64, e1 = key[4*j+1] == K64;
        bool e2 = key[4*j+2] == K64, e3 = key[4*j+3] == K64;
        unsigned long long bb0 = __ballot(e0), bb1 = __ballot(e1);
        unsigned long long bb2 = __ballot(e2), bb3 = __ballot(e3);
        int below = __popcll(bb0 & ltm) + __popcll(bb1 & ltm)
                  + __popcll(bb2 & ltm) + __popcll(bb3 & ltm);
        int base = taken + below, o = 0;
        if (e0) { if (base + o >= r) drop |= (1u << (4*j+0)); o++; }
        if (e1) { if (base + o >= r) drop |= (1u << (4*j+1)); o++; }
        if (e2) { if (base + o >= r) drop |= (1u << (4*j+2)); o++; }
        if (e3) { if (base + o >= r) drop |= (1u << (4*j+3)); o++; }
        taken += __popcll(bb0) + __popcll(bb1) + __popcll(bb2) + __popcll(bb3);
      }
    }
  }
  unsigned kmax = 0;
  #pragma unroll
  for (int e = 0; e < 32; e++)
    if (!((drop >> e) & 1u)) kmax = kmax > key[e] ? kmax : key[e];
  kmax = waveMaxU(kmax);
  float mx = invmono(kmax);
  float s = 0.f;
  #pragma unroll
  for (int e = 0; e < 32; e++)
    if (!((drop >> e) & 1u)) s += __expf(invmono(key[e]) - mx);
  s = waveSumF(s);
  float inv = 1.0f / s;
  #pragma unroll
  for (int j = 0; j < 8; j++) {
    int base = (lane << 2) + (j << 8);
    float4 o;
    o.x = ((drop >> (4*j+0)) & 1u) ? 0.f : __expf(invmono(key[4*j+0]) - mx) * inv;
    o.y = ((drop >> (4*j+1)) & 1u) ? 0.f : __expf(invmono(key[4*j+1]) - mx) * inv;
    o.z = ((drop >> (4*j+2)) & 1u) ? 0.f : __expf(invmono(key[4*j+2]) - mx) * inv;
    o.w = ((drop >> (4*j+3)) & 1u) ? 0.f : __expf(invmono(key[4*j+3]) - mx) * inv;
    *(float4*)(rp + base) = o;
  }
}

// ---------------- v_proj per-z ----------------
__global__ __launch_bounds__(256) void vproj_kernel(const float* __restrict__ v,
    const unsigned short* __restrict__ WvT, unsigned short* __restrict__ vpT) {
  __shared__ unsigned short As[128][64];
  __shared__ unsigned short Bs[128][64];
  int tid = threadIdx.x;
  int lane = tid & 63, wv = tid >> 6;
  int l31 = lane & 31, lh = lane >> 5;
  int wr = wv >> 1, wc = wv & 1;
  int z = blockIdx.z, b = z >> 3, h = z & 7;
  int m0 = blockIdx.y * 128, n0 = blockIdx.x * 128;
  const unsigned short* Ap = WvT + (size_t)(h * 512 + m0) * 512;
  const float* Bp = v + ((size_t)b * 2048 + n0) * 512;
  f32x16 acc[2][2];
  #pragma unroll
  for (int mf = 0; mf < 2; mf++)
    #pragma unroll
    for (int nf = 0; nf < 2; nf++)
      #pragma unroll
      for (int r = 0; r < 16; r++) acc[mf][nf][r] = 0.f;
  int srow = tid >> 1;
  int skc = (tid & 1) << 5;
  for (int k0 = 0; k0 < 512; k0 += 64) {
    {
      const bfrag8* s = (const bfrag8*)(Ap + (size_t)srow * 512 + k0 + skc);
      #pragma unroll
      for (int j = 0; j < 4; j++) {
        int c = (skc >> 3) + j;
        *(bfrag8*)&As[srow][((c + srow) & 7) * 8] = s[j];
      }
    }
    {
      const float* s = Bp + (size_t)srow * 512 + k0 + skc;
      #pragma unroll
      for (int j = 0; j < 4; j++) {
        float4 x0 = *(const float4*)(s + 8*j);
        float4 x1 = *(const float4*)(s + 8*j + 4);
        union { bfrag8 v; unsigned w[4]; } p;
        p.w[0] = cvtpk_bf16(x0.x, x0.y); p.w[1] = cvtpk_bf16(x0.z, x0.w);
        p.w[2] = cvtpk_bf16(x1.x, x1.y); p.w[3] = cvtpk_bf16(x1.z, x1.w);
        int c = (skc >> 3) + j;
        *(bfrag8*)&Bs[srow][((c + srow) & 7) * 8] = p.v;
      }
    }
    __syncthreads();
    #pragma unroll
    for (int ks = 0; ks < 4; ks++) {
      int qd = ks * 2 + lh;
      bfrag8 af[2], bfr[2];
      #pragma unroll
      for (int mf = 0; mf < 2; mf++) {
        int r = wr * 64 + mf * 32 + l31;
        af[mf] = *(const bfrag8*)&As[r][((qd + r) & 7) * 8];
      }
      #pragma unroll
      for (int nf = 0; nf < 2; nf++) {
        int n = wc * 64 + nf * 32 + l31;
        bfr[nf] = *(const bfrag8*)&Bs[n][((qd + n) & 7) * 8];
      }
      #pragma unroll
      for (int mf = 0; mf < 2; mf++)
        #pragma unroll
        for (int nf = 0; nf < 2; nf++)
          acc[mf][nf] = __builtin_amdgcn_mfma_f32_32x32x16_bf16(af[mf], bfr[nf], acc[mf][nf], 0, 0, 0);
    }
    __syncthreads();
  }
  #pragma unroll
  for (int mf = 0; mf < 2; mf++)
    #pragma unroll
    for (int nf = 0; nf < 2; nf++) {
      int l = n0 + wc * 64 + nf * 32 + l31;
      #pragma unroll
      for (int r = 0; r < 16; r++) {
        int d = m0 + wr * 64 + mf * 32 + (r & 3) + ((r >> 2) << 3) + (lh << 2);
        vpT[((size_t)z * 512 + d) * 2048 + l] = f2bf(acc[mf][nf][r]);
      }
    }
}

// ---------------- bf16 MFMA GEMM (fc only) ----------------
__global__ __launch_bounds__(256) void gemm_bf16_fc(const unsigned short* __restrict__ A,
    const unsigned short* __restrict__ Bt, float* __restrict__ Cout,
    int M, int N, int K) {
  __shared__ unsigned short As[64][72];
  __shared__ unsigned short Bs[128][72];
  int tid = threadIdx.x;
  int lane = tid & 63, wave = tid >> 6;
  int wr = wave >> 1, wc = wave & 1;
  int m0 = blockIdx.y * 64, n0 = blockIdx.x * 128;
  f32x4 acc[2][4];
  #pragma unroll
  for (int mi = 0; mi < 2; mi++)
    #pragma unroll
    for (int ni = 0; ni < 4; ni++) acc[mi][ni] = (f32x4){0.f, 0.f, 0.f, 0.f};
  int arow = tid >> 2, akc = (tid & 3) << 4;
  int brow = tid >> 1, bkc = (tid & 1) << 5;
  for (int k0 = 0; k0 < K; k0 += 64) {
    {
      const bfrag8* s = (const bfrag8*)(A + (size_t)(m0 + arow) * K + k0 + akc);
      *(bfrag8*)&As[arow][akc + 0] = s[0];
      *(bfrag8*)&As[arow][akc + 8] = s[1];
    }
    {
      const bfrag8* s = (const bfrag8*)(Bt + (size_t)(n0 + brow) * K + k0 + bkc);
      #pragma unroll
      for (int j = 0; j < 4; j++)
        *(bfrag8*)&Bs[brow][bkc + 8*j] = s[j];
    }
    __syncthreads();
    #pragma unroll
    for (int kh = 0; kh < 2; kh++) {
      int krd = (kh << 5) + ((lane >> 4) << 3);
      bfrag8 af[2], bfr[4];
      #pragma unroll
      for (int mi = 0; mi < 2; mi++)
        af[mi] = *(const bfrag8*)&As[wr*32 + mi*16 + (lane & 15)][krd];
      #pragma unroll
      for (int ni = 0; ni < 4; ni++)
        bfr[ni] = *(const bfrag8*)&Bs[wc*64 + ni*16 + (lane & 15)][krd];
      #pragma unroll
      for (int mi = 0; mi < 2; mi++)
        #pragma unroll
        for (int ni = 0; ni < 4; ni++)
          acc[mi][ni] = __builtin_amdgcn_mfma_f32_16x16x32_bf16(af[mi], bfr[ni], acc[mi][ni], 0, 0, 0);
    }
    __syncthreads();
  }
  #pragma unroll
  for (int mi = 0; mi < 2; mi++) {
    int rb = m0 + wr*32 + mi*16 + ((lane >> 4) << 2);
    #pragma unroll
    for (int ni = 0; ni < 4; ni++) {
      int col = n0 + wc*64 + ni*16 + (lane & 15);
      f32x4 v = acc[mi][ni];
      #pragma unroll
      for (int j = 0; j < 4; j++)
        Cout[(size_t)(rb + j)*512 + col] = v[j];
    }
  }
}

// ---------------- PV: probs[z] f32 x vpT[z] -> mixed bf16 (z-pinned, 512 blocks) ----------------
__global__ __launch_bounds__(512) void pv_kernel(const float* __restrict__ probs,
    const unsigned short* __restrict__ vpT, unsigned short* __restrict__ mixed) {
  __shared__ unsigned short As[64][64];
  __shared__ unsigned short Bs[512][64];
  int tid = threadIdx.x;
  int lane = tid & 63, wv = tid >> 6;
  int l31 = lane & 31, lh = lane >> 5;
  int bid = blockIdx.x;
  int xcd = bid & 7, idx = bid >> 3;
  int z = (xcd << 1) | (idx >> 5);
  int m0 = (idx & 31) << 6;
  const float* Ap = probs + (size_t)z * 2048 * 2048 + (size_t)m0 * 2048;
  const unsigned short* Bp = vpT + (size_t)z * 512 * 2048;
  f32x16 acc[2][2];
  #pragma unroll
  for (int mf = 0; mf < 2; mf++)
    #pragma unroll
    for (int nf = 0; nf < 2; nf++)
      #pragma unroll
      for (int r = 0; r < 16; r++) acc[mf][nf][r] = 0.f;
  int a_r = tid >> 3, a_c = tid & 7;
  for (int k0 = 0; k0 < 2048; k0 += 64) {
    {
      const float* s = Ap + (size_t)a_r * 2048 + k0 + a_c * 8;
      float4 x0 = *(const float4*)s;
      float4 x1 = *(const float4*)(s + 4);
      union { bfrag8 v; unsigned w[4]; } p;
      p.w[0] = cvtpk_bf16(x0.x, x0.y); p.w[1] = cvtpk_bf16(x0.z, x0.w);
      p.w[2] = cvtpk_bf16(x1.x, x1.y); p.w[3] = cvtpk_bf16(x1.z, x1.w);
      *(bfrag8*)&As[a_r][((a_c + a_r) & 7) * 8] = p.v;
    }
    #pragma unroll
    for (int s = 0; s < 8; s++) {
      int n = (tid >> 3) + (s << 6);
      bfrag8 vb = *(const bfrag8*)(Bp + (size_t)n * 2048 + k0 + a_c * 8);
      *(bfrag8*)&Bs[n][((a_c + n) & 7) * 8] = vb;
    }
    __syncthreads();
    #pragma unroll
    for (int ks = 0; ks < 4; ks++) {
      int qd = ks * 2 + lh;
      bfrag8 af[2], bfr[2];
      #pragma unroll
      for (int mf = 0; mf < 2; mf++) {
        int r = mf * 32 + l31;
        af[mf] = *(const bfrag8*)&As[r][((qd + r) & 7) * 8];
      }
      #pragma unroll
      for (int nf = 0; nf < 2; nf++) {
        int n = wv * 64 + nf * 32 + l31;
        bfr[nf] = *(const bfrag8*)&Bs[n][((qd + n) & 7) * 8];
      }
      #pragma unroll
      for (int mf = 0; mf < 2; mf++)
        #pragma unroll
        for (int nf = 0; nf < 2; nf++)
          acc[mf][nf] = __builtin_amdgcn_mfma_f32_32x32x16_bf16(af[mf], bfr[nf], acc[mf][nf], 0, 0, 0);
    }
    __syncthreads();
  }
  int bb = z >> 3, h = z & 7;
  #pragma unroll
  for (int mf = 0; mf < 2; mf++)
    #pragma unroll
    for (int nf = 0; nf < 2; nf++) {
      int n = wv * 64 + nf * 32 + l31;
      #pragma unroll
      for (int r = 0; r < 16; r++) {
        int row = m0 + mf * 32 + (r & 3) + ((r >> 2) << 3) + (lh << 2);
        mixed[((size_t)bb * 2048 + row) * 4096 + h * 512 + n] = f2bf(acc[mf][nf][r]);
      }
    }
}

extern "C" void kernel_launch(void* const* d_in, const int* in_sizes, int n_in,
                              void* d_out, int out_size, void* d_ws, size_t ws_size,
                              hipStream_t stream) {
  (void)in_sizes; (void)n_in; (void)out_size; (void)ws_size;
  const float* q     = (const float*)d_in[0];
  const float* k     = (const float*)d_in[1];
  const float* v     = (const float*)d_in[2];
  const int*   mask  = (const int*)d_in[3];
  const float* qmask = (const float*)d_in[4];
  const float* Wq    = (const float*)d_in[5];
  const float* Wk    = (const float*)d_in[6];
  const float* Wv    = (const float*)d_in[7];
  const float* Wfc   = (const float*)d_in[8];

  float* out   = (float*)d_out;                 // [2,2048,512]
  float* probs = out + 2097152;                 // [2,8,2048,2048] (logits then probs, in place)

  char* ws = (char*)d_ws;
  float*          qp    = (float*)(ws + 0);             // [16,2048,64] (q pre-scaled 1/8)
  float*          kp    = (float*)(ws + 8388608);       // [16,2048,64]
  unsigned short* vpT   = (unsigned short*)(ws + 16777216);  // [16,512,2048] bf16
  unsigned short* mixed = (unsigned short*)(ws + 50331648);  // [4096,4096] bf16
  unsigned*       mpack = (unsigned*)(ws + 58720256);   // [2,2048,64] u32 (inside mixed region; dead before pv)
  float*          WqT   = (float*)(ws + 83886080);      // [512,512]
  float*          WkT   = (float*)(ws + 84934656);      // [512,512]
  unsigned short* WvT   = (unsigned short*)(ws + 85983232);  // [4096,512] bf16
  unsigned short* WfcT  = (unsigned short*)(ws + 90177536);  // [512,4096] bf16

  transpose_k<0><<<dim3(16, 16),  256, 0, stream>>>(Wq,  WqT,  512, 512);
  transpose_k<0><<<dim3(16, 16),  256, 0, stream>>>(Wk,  WkT,  512, 512);
  transpose_k<1><<<dim3(128, 16), 256, 0, stream>>>(Wv,  WvT,  512, 4096);
  transpose_k<1><<<dim3(16, 128), 256, 0, stream>>>(Wfc, WfcT, 4096, 512);

  mask_pack_kernel<<<dim3(32768), 256, 0, stream>>>(mask, mpack);

  // fp32 projections, q and k merged (top-k path must be fp32-exact)
  proj_f32_kernel<<<dim3(4, 32, 2), 256, 0, stream>>>(q, k, WqT, WkT, qp, kp);

  // v_proj per (b,h)
  vproj_kernel<<<dim3(16, 4, 16), 256, 0, stream>>>(v, WvT, vpT);

  // fp32 logits with fused bit-packed mask -> probs region
  logits_mask_kernel<<<dim3(16, 16, 16), 256, 0, stream>>>(qp, kp, mpack, probs);

  // exact top-64 + softmax, in place
  topk_softmax_k<<<dim3(8192), 256, 0, stream>>>(probs, qmask);

  // PV: probs (f32->bf16 at staging) x vpT -> mixed bf16
  pv_kernel<<<dim3(512), 512, 0, stream>>>(probs, vpT, mixed);

  // fc: mixed x WfcT -> output f32
  gemm_bf16_fc<<<dim3(4, 64), 256, 0, stream>>>(mixed, WfcT, out, 4096, 512, 4096);
}